// Round 4
// baseline (442.921 us; speedup 1.0000x reference)
//
#include <hip/hip_runtime.h>
#include <hip/hip_bf16.h>

// ---------------- problem dims (fixed) ----------------
#define BB 2
#define LL 2048
#define EE 1024
#define NHH 16
#define DHH 64
#define HIDD 4096
#define MTOK (BB*LL)          // 4096 tokens
#define NQKV (NHH*3*DHH)      // 3072

typedef __attribute__((ext_vector_type(8))) short bf16x8;   // 8 bf16 in 4 VGPRs
typedef __attribute__((ext_vector_type(4))) float f32x4;

#define MFMA16(a,b,c) __builtin_amdgcn_mfma_f32_16x16x32_bf16(a,b,c,0,0,0)

static __device__ __forceinline__ void gload_lds16(const void* g, void* lds) {
  __builtin_amdgcn_global_load_lds(
      (const __attribute__((address_space(1))) unsigned int*)g,
      (__attribute__((address_space(3))) unsigned int*)lds, 16, 0, 0);
}

// ---------------- weight fp32 -> bf16 transpose-convert ----------------
__global__ __launch_bounds__(256)
void convT_kernel(const float* __restrict__ W, __hip_bfloat16* __restrict__ WT,
                  int K, int N) {
  __shared__ float tile[32][33];
  const int tx = threadIdx.x & 31, ty = threadIdx.x >> 5;
  const int n0 = blockIdx.x * 32, k0 = blockIdx.y * 32;
#pragma unroll
  for (int i = 0; i < 4; ++i)
    tile[ty + i*8][tx] = W[(size_t)(k0 + ty + i*8) * N + n0 + tx];
  __syncthreads();
#pragma unroll
  for (int i = 0; i < 4; ++i)
    WT[(size_t)(n0 + ty + i*8) * K + k0 + tx] = __float2bfloat16(tile[tx][ty + i*8]);
}

// ---------------- V transpose: qkv -> VT[bh][dh][L] ----------------
__global__ __launch_bounds__(256)
void vtrans_kernel(const __hip_bfloat16* __restrict__ qkv,
                   __hip_bfloat16* __restrict__ VT) {
  __shared__ ushort tile[32][34];
  const int tx = threadIdx.x & 31, ty = threadIdx.x >> 5;
  const int tok0 = blockIdx.x * 32;
  const int dh0  = blockIdx.y * 32;
  const int bh   = blockIdx.z;
  const int b = bh >> 4, h = bh & 15;
  const ushort* src = (const ushort*)qkv;
#pragma unroll
  for (int i = 0; i < 4; ++i)
    tile[ty + i*8][tx] =
      src[(size_t)(b*LL + tok0 + ty + i*8) * NQKV + h*192 + 128 + dh0 + tx];
  __syncthreads();
  ushort* dst = (ushort*)VT;
#pragma unroll
  for (int i = 0; i < 4; ++i)
    dst[(size_t)(bh*DHH + dh0 + ty + i*8) * LL + tok0 + tx] = tile[tx][ty + i*8];
}

// ---------------- LayerNorm (fp32 in, bf16 out), row = 1024 ----------------
__global__ __launch_bounds__(256)
void ln_kernel(const float* __restrict__ in, const float* __restrict__ g,
               const float* __restrict__ be, __hip_bfloat16* __restrict__ out) {
  const int row = blockIdx.x;
  const int t = threadIdx.x;
  const float4 v = ((const float4*)(in + (size_t)row * EE))[t];
  float s = v.x + v.y + v.z + v.w;
  float q = v.x*v.x + v.y*v.y + v.z*v.z + v.w*v.w;
#pragma unroll
  for (int off = 32; off >= 1; off >>= 1) {
    s += __shfl_xor(s, off);
    q += __shfl_xor(q, off);
  }
  __shared__ float ps[4], pq[4];
  if ((t & 63) == 0) { ps[t >> 6] = s; pq[t >> 6] = q; }
  __syncthreads();
  s = ps[0] + ps[1] + ps[2] + ps[3];
  q = pq[0] + pq[1] + pq[2] + pq[3];
  const float mean = s * (1.0f / EE);
  const float rstd = rsqrtf(q * (1.0f / EE) - mean * mean + 1e-5f);
  const float4 gg = ((const float4*)g)[t];
  const float4 bb = ((const float4*)be)[t];
  union { ushort4 u; __hip_bfloat16 h[4]; } o;
  o.h[0] = __float2bfloat16((v.x - mean) * rstd * gg.x + bb.x);
  o.h[1] = __float2bfloat16((v.y - mean) * rstd * gg.y + bb.y);
  o.h[2] = __float2bfloat16((v.z - mean) * rstd * gg.z + bb.z);
  o.h[3] = __float2bfloat16((v.w - mean) * rstd * gg.w + bb.w);
  ((ushort4*)(out + (size_t)row * EE))[t] = o.u;
}

// ---------------- GEMM body: C = A(MxK) * BT(NxK)^T (unchanged r3) --------
template<int BN, int OUT_BF16, int HAS_BIAS, int HAS_RES>
__device__ __forceinline__ void gemm_body(
    const __hip_bfloat16* __restrict__ A, const __hip_bfloat16* __restrict__ BT,
    void* __restrict__ Cv, const float* __restrict__ bias,
    const float* __restrict__ res, int M, int N, int K, int lda, int ldb) {
  constexpr int NF = BN / 32;
  __shared__ alignas(16) __hip_bfloat16 sA[2][128 * 32];
  __shared__ alignas(16) __hip_bfloat16 sB[2][BN * 32];
  const int t = threadIdx.x;
  const int wv = t >> 6, l = t & 63;
  const int lr = l & 15, lk = (l >> 4) * 8;

  const int nwg = gridDim.x * gridDim.y;
  int wg = blockIdx.y * gridDim.x + blockIdx.x;
  wg = (wg & 7) * (nwg >> 3) + (wg >> 3);
  const int bx = wg % gridDim.x, by = wg / gridDim.x;
  const int m0 = by * 128, n0 = bx * BN;

  const int wrow = (wv >> 1) * 64;
  const int wcol = (wv & 1) * (BN / 2);
  const int srow = t >> 2, scol = (t & 3) * 8;
  const __hip_bfloat16* gA = A + (size_t)(m0 + srow) * lda + scol;
  const __hip_bfloat16* gB = BT + (size_t)(n0 + srow) * ldb + scol;

  auto stage = [&](int buf, int k0) {
    char* dA = (char*)(&sA[buf][0]) + wv * 1024;
    gload_lds16(gA + k0, dA);
    gload_lds16(gA + (size_t)64 * lda + k0, dA + 4096);
    char* dB = (char*)(&sB[buf][0]) + wv * 1024;
    gload_lds16(gB + k0, dB);
    if constexpr (BN == 128)
      gload_lds16(gB + (size_t)64 * ldb + k0, dB + 4096);
  };

  f32x4 acc[4][NF] = {};

  auto compute = [&](int buf) {
    bf16x8 af[4], bfv[NF];
#pragma unroll
    for (int mi = 0; mi < 4; ++mi)
      af[mi] = *(const bf16x8*)(&sA[buf][(wrow + mi * 16 + lr) * 32 + lk]);
#pragma unroll
    for (int ni = 0; ni < NF; ++ni)
      bfv[ni] = *(const bf16x8*)(&sB[buf][(wcol + ni * 16 + lr) * 32 + lk]);
#pragma unroll
    for (int mi = 0; mi < 4; ++mi)
#pragma unroll
      for (int ni = 0; ni < NF; ++ni)
        acc[mi][ni] = MFMA16(af[mi], bfv[ni], acc[mi][ni]);
  };

  stage(0, 0);
  __syncthreads();
  for (int k0 = 0; k0 < K; k0 += 64) {
    stage(1, k0 + 32);
    compute(0);
    __syncthreads();
    if (k0 + 64 < K) stage(0, k0 + 64);
    compute(1);
    __syncthreads();
  }

  const int rbase = (l >> 4) * 4;
#pragma unroll
  for (int mi = 0; mi < 4; ++mi) {
#pragma unroll
    for (int ni = 0; ni < NF; ++ni) {
#pragma unroll
      for (int r = 0; r < 4; ++r) {
        const int row = m0 + wrow + mi * 16 + rbase + r;
        const int col = n0 + wcol + ni * 16 + lr;
        float v = acc[mi][ni][r];
        if constexpr (HAS_BIAS) v += bias[col];
        if constexpr (HAS_RES)  v += res[(size_t)row * N + col];
        if constexpr (OUT_BF16)
          ((__hip_bfloat16*)Cv)[(size_t)row * N + col] = __float2bfloat16(v);
        else
          ((float*)Cv)[(size_t)row * N + col] = v;
      }
    }
  }
}

__global__ __launch_bounds__(256)
void gemm_qkv(const __hip_bfloat16* A, const __hip_bfloat16* BT, __hip_bfloat16* C) {
  gemm_body<128,1,0,0>(A, BT, C, nullptr, nullptr, MTOK, NQKV, EE, EE, EE);
}
__global__ __launch_bounds__(256)
void gemm_wout(const __hip_bfloat16* A, const __hip_bfloat16* BT, float* C,
               const float* bias, const float* res) {
  gemm_body<128,0,1,1>(A, BT, C, bias, res, MTOK, EE, EE, EE, EE);
}
__global__ __launch_bounds__(256)
void gemm_ffn1(const __hip_bfloat16* A, const __hip_bfloat16* BT, __hip_bfloat16* C,
               const float* bias) {
  gemm_body<128,1,1,0>(A, BT, C, bias, nullptr, MTOK, HIDD, EE, EE, EE);
}
__global__ __launch_bounds__(256)
void gemm_ffn2p(const __hip_bfloat16* A, const __hip_bfloat16* BT,
                float* P0, float* P1) {
  const int ks = blockIdx.z;
  float* P = ks ? P1 : P0;
  gemm_body<64,0,0,0>(A + ks * 2048, BT + ks * 2048, P, nullptr, nullptr,
                      MTOK, EE, 2048, HIDD, HIDD);
}

__global__ __launch_bounds__(256)
void ffn2_reduce(const float4* __restrict__ P0, const float4* __restrict__ P1,
                 const float4* __restrict__ x, const float* __restrict__ b2,
                 float4* __restrict__ out) {
  const int n4 = MTOK * EE / 4;
  for (int i = blockIdx.x * 256 + threadIdx.x; i < n4; i += 2048 * 256) {
    const float4 b = ((const float4*)b2)[i & 255];
    const float4 p = P0[i], q = P1[i], xx = x[i];
    float4 o;
    o.x = xx.x + b.x + p.x + q.x;
    o.y = xx.y + b.y + p.y + q.y;
    o.z = xx.z + b.z + p.z + q.z;
    o.w = xx.w + b.w + p.w + q.w;
    out[i] = o;
  }
}

// ---------------- causal flash attention v3: swapped-QK softmax ------------
// grid (L/64, NH, B), 256 threads = 4 independent waves, 16 q-rows each.
// S^T = mfma(A=K, B=Q): lane owns q = qw + (lane&15); its 16 toks/tile are
// in-register -> row-reduce = in-lane tree + 2 shfl_xor (16,32).
// P round-trips via wave-private LDS (packed b64 writes) into PV A-frags.
__global__ __launch_bounds__(256)
void attn_kernel(const __hip_bfloat16* __restrict__ qkv,
                 const __hip_bfloat16* __restrict__ VT,
                 __hip_bfloat16* __restrict__ out) {
  __shared__ alignas(16) __hip_bfloat16 sP[4][16 * 72];   // per-wave [16q][64tok pad72]
  const int t = threadIdx.x;
  const int wv = t >> 6, l = t & 63;
  const int lr = l & 15, lg = l >> 4, lk = lg * 8;
  const int hh = blockIdx.y, b = blockIdx.z;
  int qx = blockIdx.x;
  if (b == 1) qx = 31 - qx;                 // causal load balance
  const int qw = qx * 64 + wv * 16;
  const size_t rowbase = (size_t)b * LL;
  const int hoff = hh * (3 * DHH);
  const __hip_bfloat16* vt = VT + (size_t)((b * NHH + hh) * DHH) * LL;

  // Q fragment (this lane's q-row = qw+lr), two dh halves
  bf16x8 qa0, qa1;
  {
    const __hip_bfloat16* qp = qkv + (rowbase + qw + lr) * NQKV + hoff;
    qa0 = *(const bf16x8*)(qp + lk);
    qa1 = *(const bf16x8*)(qp + 32 + lk);
  }

  f32x4 o[4] = {};
  float mrun = -INFINITY, lrun = 0.f;
  __hip_bfloat16* sp = sP[wv];
  const __hip_bfloat16* kbase = qkv + rowbase * NQKV + hoff + DHH;
  const int nt = (qw + 79) >> 6;            // covers toks 0..qw+15

  for (int kt = 0; kt < nt; ++kt) {
    const int t0 = kt * 64;
    // V fragments early (L2-hit; hidden under QK^T + softmax)
    bf16x8 vb[4][2];
#pragma unroll
    for (int ni = 0; ni < 4; ++ni)
#pragma unroll
      for (int ks = 0; ks < 2; ++ks)
        vb[ni][ks] = *(const bf16x8*)(vt + (size_t)(ni*16 + lr) * LL + t0 + ks*32 + lk);

    // S^T tiles: st[tg][r] = S[tok = t0+tg*16+lg*4+r][q = qw+lr]
    f32x4 st[4];
    __builtin_amdgcn_s_setprio(1);
#pragma unroll
    for (int tg = 0; tg < 4; ++tg) {
      const __hip_bfloat16* kp = kbase + (size_t)(t0 + tg*16 + lr) * NQKV;
      bf16x8 kb0 = *(const bf16x8*)(kp + lk);
      bf16x8 kb1 = *(const bf16x8*)(kp + 32 + lk);
      f32x4 z = {0.f, 0.f, 0.f, 0.f};
      z = MFMA16(kb0, qa0, z);          // A=K, B=Q -> S^T
      z = MFMA16(kb1, qa1, z);
      st[tg] = z;
    }
    __builtin_amdgcn_s_setprio(0);

    // scale + causal mask (lane's own q-row)
    const bool edge = (kt == nt - 1);
    float tmax = -INFINITY;
#pragma unroll
    for (int tg = 0; tg < 4; ++tg)
#pragma unroll
      for (int r = 0; r < 4; ++r) {
        float v = st[tg][r] * 0.125f;   // 1/sqrt(64)
        if (edge && (t0 + tg*16 + lg*4 + r > qw + lr)) v = -INFINITY;
        st[tg][r] = v;
        tmax = fmaxf(tmax, v);
      }
    // row-reduce: values for this q live in lanes {lr, lr+16, lr+32, lr+48}
    tmax = fmaxf(tmax, __shfl_xor(tmax, 16));
    tmax = fmaxf(tmax, __shfl_xor(tmax, 32));
    const float mnew = fmaxf(mrun, tmax);
    const float corr = __expf(mrun - mnew);
    float rs = 0.f;
#pragma unroll
    for (int tg = 0; tg < 4; ++tg) {
      const float p0 = __expf(st[tg][0] - mnew);
      const float p1 = __expf(st[tg][1] - mnew);
      const float p2 = __expf(st[tg][2] - mnew);
      const float p3 = __expf(st[tg][3] - mnew);
      rs += (p0 + p1) + (p2 + p3);
      union { ushort4 u; __hip_bfloat16 h[4]; } pk;
      pk.h[0] = __float2bfloat16(p0);
      pk.h[1] = __float2bfloat16(p1);
      pk.h[2] = __float2bfloat16(p2);
      pk.h[3] = __float2bfloat16(p3);
      *(ushort4*)(sp + lr*72 + tg*16 + lg*4) = pk.u;   // packed 8B write
    }
    rs += __shfl_xor(rs, 16);
    rs += __shfl_xor(rs, 32);
    lrun = lrun * corr + rs;
    mrun = mnew;

    // broadcast corr to the o-accumulator row layout (q = qw + lg*4 + r)
    float corr_o[4];
#pragma unroll
    for (int r = 0; r < 4; ++r)
      corr_o[r] = __shfl(corr, lg*20 + r);   // lane lg*16 + (lg*4+r)
#pragma unroll
    for (int ni = 0; ni < 4; ++ni)
#pragma unroll
      for (int r = 0; r < 4; ++r) o[ni][r] *= corr_o[r];

    // PV: O += P(16x64) V(64x64); A-frag from wave-private LDS
    bf16x8 pf0 = *(const bf16x8*)(sp + lr*72 + lk);
    bf16x8 pf1 = *(const bf16x8*)(sp + lr*72 + 32 + lk);
    __builtin_amdgcn_s_setprio(1);
#pragma unroll
    for (int ni = 0; ni < 4; ++ni) {
      o[ni] = MFMA16(pf0, vb[ni][0], o[ni]);
      o[ni] = MFMA16(pf1, vb[ni][1], o[ni]);
    }
    __builtin_amdgcn_s_setprio(0);
  }

  // normalize (1/l for q = qw+lg*4+r lives in lane lg*20+r) + write
  float linv[4];
#pragma unroll
  for (int r = 0; r < 4; ++r)
    linv[r] = 1.0f / __shfl(lrun, lg*20 + r);
#pragma unroll
  for (int r = 0; r < 4; ++r) {
    const int qr = qw + lg*4 + r;
    __hip_bfloat16* op = out + (rowbase + qr) * (NHH * DHH) + hh * DHH;
#pragma unroll
    for (int ni = 0; ni < 4; ++ni)
      op[ni*16 + lr] = __float2bfloat16(o[ni][r] * linv[r]);
  }
}

// ---------------- launch ----------------
extern "C" void kernel_launch(void* const* d_in, const int* in_sizes, int n_in,
                              void* d_out, int out_size, void* d_ws, size_t ws_size,
                              hipStream_t stream) {
  (void)in_sizes; (void)n_in; (void)out_size; (void)ws_size;
  const float* x    = (const float*)d_in[0];
  const float* Wa   = (const float*)d_in[1];
  const float* Wout = (const float*)d_in[2];
  const float* bout = (const float*)d_in[3];
  const float* W1   = (const float*)d_in[4];
  const float* b1   = (const float*)d_in[5];
  const float* W2   = (const float*)d_in[6];
  const float* b2   = (const float*)d_in[7];
  const float* g1   = (const float*)d_in[8];
  const float* be1  = (const float*)d_in[9];
  const float* g2   = (const float*)d_in[10];
  const float* be2  = (const float*)d_in[11];

  char* ws = (char*)d_ws;
  __hip_bfloat16* WaT   = (__hip_bfloat16*)(ws + 0);         // [0,6M)
  __hip_bfloat16* WoutT = (__hip_bfloat16*)(ws + 6291456);   // [6,8M)
  __hip_bfloat16* W1T   = (__hip_bfloat16*)(ws + 8388608);   // [8,16M)
  __hip_bfloat16* W2T   = (__hip_bfloat16*)(ws + 16777216);  // [16,24M)
  __hip_bfloat16* o1    = (__hip_bfloat16*)(ws + 25165824);  // [24,32M)
  __hip_bfloat16* qkv   = (__hip_bfloat16*)(ws + 33554432);  // [32,56M)
  __hip_bfloat16* VT    = (__hip_bfloat16*)(ws + 58720256);  // [56,64M)
  __hip_bfloat16* attnb = (__hip_bfloat16*)(ws + 67108864);  // [64,72M)
  float*          ybuf  = (float*)(ws + 33554432);           // alias qkv
  __hip_bfloat16* ln2b  = (__hip_bfloat16*)(ws + 25165824);  // alias o1
  __hip_bfloat16* hbuf  = (__hip_bfloat16*)(ws + 50331648);  // [48,80M)
  float*          P0    = (float*)(ws + 0);                  // alias weights
  float*          P1    = (float*)(ws + 33554432);           // alias ybuf

  convT_kernel<<<dim3(NQKV/32, EE/32), 256, 0, stream>>>(Wa, WaT, EE, NQKV);
  convT_kernel<<<dim3(EE/32, EE/32), 256, 0, stream>>>(Wout, WoutT, EE, EE);
  convT_kernel<<<dim3(HIDD/32, EE/32), 256, 0, stream>>>(W1, W1T, EE, HIDD);
  convT_kernel<<<dim3(EE/32, HIDD/32), 256, 0, stream>>>(W2, W2T, HIDD, EE);
  ln_kernel<<<MTOK, 256, 0, stream>>>(x, g1, be1, o1);
  gemm_qkv<<<dim3(NQKV/128, MTOK/128), 256, 0, stream>>>(o1, WaT, qkv);
  vtrans_kernel<<<dim3(LL/32, DHH/32, BB*NHH), 256, 0, stream>>>(qkv, VT);
  attn_kernel<<<dim3(LL/64, NHH, BB), 256, 0, stream>>>(qkv, VT, attnb);
  gemm_wout<<<dim3(EE/128, MTOK/128), 256, 0, stream>>>(attnb, WoutT, ybuf, bout, x);
  ln_kernel<<<MTOK, 256, 0, stream>>>(ybuf, g2, be2, ln2b);
  gemm_ffn1<<<dim3(HIDD/128, MTOK/128), 256, 0, stream>>>(ln2b, W1T, hbuf, b1);
  gemm_ffn2p<<<dim3(EE/64, MTOK/128, 2), 256, 0, stream>>>(hbuf, W2T, P0, P1);
  ffn2_reduce<<<2048, 256, 0, stream>>>((const float4*)P0, (const float4*)P1,
                                        (const float4*)x, b2, (float4*)d_out);
}

// Round 10
// 416.687 us; speedup vs baseline: 1.0630x; 1.0630x over previous
//
#include <hip/hip_runtime.h>
#include <hip/hip_bf16.h>

// ---------------- problem dims (fixed) ----------------
#define BB 2
#define LL 2048
#define EE 1024
#define NHH 16
#define DHH 64
#define HIDD 4096
#define MTOK (BB*LL)          // 4096 tokens
#define NQKV (NHH*3*DHH)      // 3072

typedef __attribute__((ext_vector_type(8))) short bf16x8;   // 8 bf16 in 4 VGPRs
typedef __attribute__((ext_vector_type(4))) float f32x4;

#define MFMA16(a,b,c) __builtin_amdgcn_mfma_f32_16x16x32_bf16(a,b,c,0,0,0)

static __device__ __forceinline__ void gload_lds16(const void* g, void* lds) {
  __builtin_amdgcn_global_load_lds(
      (const __attribute__((address_space(1))) unsigned int*)g,
      (__attribute__((address_space(3))) unsigned int*)lds, 16, 0, 0);
}

// ---------------- weight fp32 -> bf16 transpose-convert ----------------
__global__ __launch_bounds__(256)
void convT_kernel(const float* __restrict__ W, __hip_bfloat16* __restrict__ WT,
                  int K, int N) {
  __shared__ float tile[32][33];
  const int tx = threadIdx.x & 31, ty = threadIdx.x >> 5;
  const int n0 = blockIdx.x * 32, k0 = blockIdx.y * 32;
#pragma unroll
  for (int i = 0; i < 4; ++i)
    tile[ty + i*8][tx] = W[(size_t)(k0 + ty + i*8) * N + n0 + tx];
  __syncthreads();
#pragma unroll
  for (int i = 0; i < 4; ++i)
    WT[(size_t)(n0 + ty + i*8) * K + k0 + tx] = __float2bfloat16(tile[tx][ty + i*8]);
}

// ---------------- V transpose: qkv -> VT[bh][dh][L] ----------------
__global__ __launch_bounds__(256)
void vtrans_kernel(const __hip_bfloat16* __restrict__ qkv,
                   __hip_bfloat16* __restrict__ VT) {
  __shared__ ushort tile[32][34];
  const int tx = threadIdx.x & 31, ty = threadIdx.x >> 5;
  const int tok0 = blockIdx.x * 32;
  const int dh0  = blockIdx.y * 32;
  const int bh   = blockIdx.z;
  const int b = bh >> 4, h = bh & 15;
  const ushort* src = (const ushort*)qkv;
#pragma unroll
  for (int i = 0; i < 4; ++i)
    tile[ty + i*8][tx] =
      src[(size_t)(b*LL + tok0 + ty + i*8) * NQKV + h*192 + 128 + dh0 + tx];
  __syncthreads();
  ushort* dst = (ushort*)VT;
#pragma unroll
  for (int i = 0; i < 4; ++i)
    dst[(size_t)(bh*DHH + dh0 + ty + i*8) * LL + tok0 + tx] = tile[tx][ty + i*8];
}

// ---------------- LayerNorm (fp32 in, bf16 out), row = 1024 ----------------
__global__ __launch_bounds__(256)
void ln_kernel(const float* __restrict__ in, const float* __restrict__ g,
               const float* __restrict__ be, __hip_bfloat16* __restrict__ out) {
  const int row = blockIdx.x;
  const int t = threadIdx.x;
  const float4 v = ((const float4*)(in + (size_t)row * EE))[t];
  float s = v.x + v.y + v.z + v.w;
  float q = v.x*v.x + v.y*v.y + v.z*v.z + v.w*v.w;
#pragma unroll
  for (int off = 32; off >= 1; off >>= 1) {
    s += __shfl_xor(s, off);
    q += __shfl_xor(q, off);
  }
  __shared__ float ps[4], pq[4];
  if ((t & 63) == 0) { ps[t >> 6] = s; pq[t >> 6] = q; }
  __syncthreads();
  s = ps[0] + ps[1] + ps[2] + ps[3];
  q = pq[0] + pq[1] + pq[2] + pq[3];
  const float mean = s * (1.0f / EE);
  const float rstd = rsqrtf(q * (1.0f / EE) - mean * mean + 1e-5f);
  const float4 gg = ((const float4*)g)[t];
  const float4 bb = ((const float4*)be)[t];
  union { ushort4 u; __hip_bfloat16 h[4]; } o;
  o.h[0] = __float2bfloat16((v.x - mean) * rstd * gg.x + bb.x);
  o.h[1] = __float2bfloat16((v.y - mean) * rstd * gg.y + bb.y);
  o.h[2] = __float2bfloat16((v.z - mean) * rstd * gg.z + bb.z);
  o.h[3] = __float2bfloat16((v.w - mean) * rstd * gg.w + bb.w);
  ((ushort4*)(out + (size_t)row * EE))[t] = o.u;
}

// ---------------- GEMM body (unchanged from r3) ----------------
template<int BN, int OUT_BF16, int HAS_BIAS, int HAS_RES>
__device__ __forceinline__ void gemm_body(
    const __hip_bfloat16* __restrict__ A, const __hip_bfloat16* __restrict__ BT,
    void* __restrict__ Cv, const float* __restrict__ bias,
    const float* __restrict__ res, int M, int N, int K, int lda, int ldb) {
  constexpr int NF = BN / 32;
  __shared__ alignas(16) __hip_bfloat16 sA[2][128 * 32];
  __shared__ alignas(16) __hip_bfloat16 sB[2][BN * 32];
  const int t = threadIdx.x;
  const int wv = t >> 6, l = t & 63;
  const int lr = l & 15, lk = (l >> 4) * 8;

  const int nwg = gridDim.x * gridDim.y;
  int wg = blockIdx.y * gridDim.x + blockIdx.x;
  wg = (wg & 7) * (nwg >> 3) + (wg >> 3);
  const int bx = wg % gridDim.x, by = wg / gridDim.x;
  const int m0 = by * 128, n0 = bx * BN;

  const int wrow = (wv >> 1) * 64;
  const int wcol = (wv & 1) * (BN / 2);
  const int srow = t >> 2, scol = (t & 3) * 8;
  const __hip_bfloat16* gA = A + (size_t)(m0 + srow) * lda + scol;
  const __hip_bfloat16* gB = BT + (size_t)(n0 + srow) * ldb + scol;

  auto stage = [&](int buf, int k0) {
    char* dA = (char*)(&sA[buf][0]) + wv * 1024;
    gload_lds16(gA + k0, dA);
    gload_lds16(gA + (size_t)64 * lda + k0, dA + 4096);
    char* dB = (char*)(&sB[buf][0]) + wv * 1024;
    gload_lds16(gB + k0, dB);
    if constexpr (BN == 128)
      gload_lds16(gB + (size_t)64 * ldb + k0, dB + 4096);
  };

  f32x4 acc[4][NF] = {};

  auto compute = [&](int buf) {
    bf16x8 af[4], bfv[NF];
#pragma unroll
    for (int mi = 0; mi < 4; ++mi)
      af[mi] = *(const bf16x8*)(&sA[buf][(wrow + mi * 16 + lr) * 32 + lk]);
#pragma unroll
    for (int ni = 0; ni < NF; ++ni)
      bfv[ni] = *(const bf16x8*)(&sB[buf][(wcol + ni * 16 + lr) * 32 + lk]);
#pragma unroll
    for (int mi = 0; mi < 4; ++mi)
#pragma unroll
      for (int ni = 0; ni < NF; ++ni)
        acc[mi][ni] = MFMA16(af[mi], bfv[ni], acc[mi][ni]);
  };

  stage(0, 0);
  __syncthreads();
  for (int k0 = 0; k0 < K; k0 += 64) {
    stage(1, k0 + 32);
    compute(0);
    __syncthreads();
    if (k0 + 64 < K) stage(0, k0 + 64);
    compute(1);
    __syncthreads();
  }

  const int rbase = (l >> 4) * 4;
#pragma unroll
  for (int mi = 0; mi < 4; ++mi) {
#pragma unroll
    for (int ni = 0; ni < NF; ++ni) {
#pragma unroll
      for (int r = 0; r < 4; ++r) {
        const int row = m0 + wrow + mi * 16 + rbase + r;
        const int col = n0 + wcol + ni * 16 + lr;
        float v = acc[mi][ni][r];
        if constexpr (HAS_BIAS) v += bias[col];
        if constexpr (HAS_RES)  v += res[(size_t)row * N + col];
        if constexpr (OUT_BF16)
          ((__hip_bfloat16*)Cv)[(size_t)row * N + col] = __float2bfloat16(v);
        else
          ((float*)Cv)[(size_t)row * N + col] = v;
      }
    }
  }
}

__global__ __launch_bounds__(256)
void gemm_qkv(const __hip_bfloat16* A, const __hip_bfloat16* BT, __hip_bfloat16* C) {
  gemm_body<128,1,0,0>(A, BT, C, nullptr, nullptr, MTOK, NQKV, EE, EE, EE);
}
__global__ __launch_bounds__(256)
void gemm_wout(const __hip_bfloat16* A, const __hip_bfloat16* BT, float* C,
               const float* bias, const float* res) {
  gemm_body<128,0,1,1>(A, BT, C, bias, res, MTOK, EE, EE, EE, EE);
}
__global__ __launch_bounds__(256)
void gemm_ffn1(const __hip_bfloat16* A, const __hip_bfloat16* BT, __hip_bfloat16* C,
               const float* bias) {
  gemm_body<128,1,1,0>(A, BT, C, bias, nullptr, MTOK, HIDD, EE, EE, EE);
}
__global__ __launch_bounds__(256)
void gemm_ffn2p(const __hip_bfloat16* A, const __hip_bfloat16* BT,
                float* P0, float* P1) {
  const int ks = blockIdx.z;
  float* P = ks ? P1 : P0;
  gemm_body<64,0,0,0>(A + ks * 2048, BT + ks * 2048, P, nullptr, nullptr,
                      MTOK, EE, 2048, HIDD, HIDD);
}

__global__ __launch_bounds__(256)
void ffn2_reduce(const float4* __restrict__ P0, const float4* __restrict__ P1,
                 const float4* __restrict__ x, const float* __restrict__ b2,
                 float4* __restrict__ out) {
  const int n4 = MTOK * EE / 4;
  for (int i = blockIdx.x * 256 + threadIdx.x; i < n4; i += 2048 * 256) {
    const float4 b = ((const float4*)b2)[i & 255];
    const float4 p = P0[i], q = P1[i], xx = x[i];
    float4 o;
    o.x = xx.x + b.x + p.x + q.x;
    o.y = xx.y + b.y + p.y + q.y;
    o.z = xx.z + b.z + p.z + q.z;
    o.w = xx.w + b.w + p.w + q.w;
    out[i] = o;
  }
}

// ---------------- causal flash attention v4 ----------------
// Hybrid of v2 geometry + v3 swapped-QK softmax + XCD-local (b,h) mapping.
// grid 512 blocks (logical: 16 q-tiles x 16 heads x 2 batch), 4 waves/block,
// 32 q-rows/wave. All 16 q-tiles of a (b,h) land on ONE XCD (K/V/VT ~3MB/XCD
// fits 4MB L2); causal balance via (k,15-k) q-tile pairing per CU.
// S^T = mfma(A=K, B=Q): lane owns q = qw + qg*16 + (lane&15); 16 toks/tile
// in-register -> row-reduce = in-lane tree + 2 shfl_xor. No __syncthreads.
__global__ __launch_bounds__(256)
void attn_kernel(const __hip_bfloat16* __restrict__ qkv,
                 const __hip_bfloat16* __restrict__ VT,
                 __hip_bfloat16* __restrict__ out) {
  __shared__ alignas(16) __hip_bfloat16 sP[4][32 * 72];   // per-wave [32q][64tok pad72]
  const int t = threadIdx.x;
  const int wv = t >> 6, l = t & 63;
  const int lr = l & 15, lg = l >> 4, lk = lg * 8;

  // XCD-aware remap (512 blocks / 8 XCDs = 64 per XCD = 4 (b,h) x 16 q-tiles)
  const int f = blockIdx.z * (gridDim.y * gridDim.x)
              + blockIdx.y * gridDim.x + blockIdx.x;
  const int xcd = f & 7, s = f >> 3;
  const int bh = xcd * 4 + (s & 3);
  const int i = s >> 2;                    // 0..15
  const int qt = (i < 8) ? i : 23 - i;     // CU pairing (k, 15-k): const work
  const int b = bh >> 4, hh = bh & 15;
  const int qw = qt * 128 + wv * 32;

  const size_t rowbase = (size_t)b * LL;
  const int hoff = hh * (3 * DHH);
  const __hip_bfloat16* vt = VT + (size_t)((b * NHH + hh) * DHH) * LL;

  // Q fragments (B-operand of swapped QK^T): lane's q-col = qw+qg*16+lr
  bf16x8 qa[2][2];
#pragma unroll
  for (int qg = 0; qg < 2; ++qg)
#pragma unroll
    for (int h = 0; h < 2; ++h)
      qa[qg][h] = *(const bf16x8*)(qkv + (rowbase + qw + qg*16 + lr) * NQKV
                                   + hoff + h*32 + lk);

  f32x4 o[2][4] = {};
  float mrun[2] = {-INFINITY, -INFINITY}, lrun[2] = {0.f, 0.f};
  __hip_bfloat16* sp = sP[wv];
  const __hip_bfloat16* kbase = qkv + rowbase * NQKV + hoff + DHH;
  const int nt = (qw >> 6) + 1;            // covers toks 0..qw+31

  for (int kt = 0; kt < nt; ++kt) {
    const int t0 = kt * 64;
    // V fragments early (L2-local; hidden under QK^T + softmax)
    bf16x8 vb[4][2];
#pragma unroll
    for (int ni = 0; ni < 4; ++ni)
#pragma unroll
      for (int ks = 0; ks < 2; ++ks)
        vb[ni][ks] = *(const bf16x8*)(vt + (size_t)(ni*16 + lr) * LL + t0 + ks*32 + lk);

    // S^T: st[qg][tg][r] = S[tok = t0+tg*16+lg*4+r][q = qw+qg*16+lr]
    f32x4 st[2][4];
    __builtin_amdgcn_s_setprio(1);
#pragma unroll
    for (int tg = 0; tg < 4; ++tg) {
      const __hip_bfloat16* kp = kbase + (size_t)(t0 + tg*16 + lr) * NQKV;
      bf16x8 kb0 = *(const bf16x8*)(kp + lk);
      bf16x8 kb1 = *(const bf16x8*)(kp + 32 + lk);
#pragma unroll
      for (int qg = 0; qg < 2; ++qg) {
        f32x4 z = {0.f, 0.f, 0.f, 0.f};
        z = MFMA16(kb0, qa[qg][0], z);
        z = MFMA16(kb1, qa[qg][1], z);
        st[qg][tg] = z;
      }
    }
    __builtin_amdgcn_s_setprio(0);

    const bool edge = (kt == nt - 1);
    float corrv[2];
#pragma unroll
    for (int qg = 0; qg < 2; ++qg) {
      const int q = qw + qg*16 + lr;       // this lane's q-row
      float tmax = -INFINITY;
#pragma unroll
      for (int tg = 0; tg < 4; ++tg)
#pragma unroll
        for (int r = 0; r < 4; ++r) {
          float v = st[qg][tg][r] * 0.125f;   // 1/sqrt(64)
          if (edge && (t0 + tg*16 + lg*4 + r > q)) v = -INFINITY;
          st[qg][tg][r] = v;
          tmax = fmaxf(tmax, v);
        }
      tmax = fmaxf(tmax, __shfl_xor(tmax, 16));
      tmax = fmaxf(tmax, __shfl_xor(tmax, 32));
      const float mnew = fmaxf(mrun[qg], tmax);
      corrv[qg] = __expf(mrun[qg] - mnew);
      float rs = 0.f;
#pragma unroll
      for (int tg = 0; tg < 4; ++tg) {
        const float p0 = __expf(st[qg][tg][0] - mnew);
        const float p1 = __expf(st[qg][tg][1] - mnew);
        const float p2 = __expf(st[qg][tg][2] - mnew);
        const float p3 = __expf(st[qg][tg][3] - mnew);
        rs += (p0 + p1) + (p2 + p3);
        union { ushort4 u; __hip_bfloat16 h[4]; } pk;
        pk.h[0] = __float2bfloat16(p0);
        pk.h[1] = __float2bfloat16(p1);
        pk.h[2] = __float2bfloat16(p2);
        pk.h[3] = __float2bfloat16(p3);
        *(ushort4*)(sp + (qg*16 + lr)*72 + tg*16 + lg*4) = pk.u;  // 8B packed
      }
      rs += __shfl_xor(rs, 16);
      rs += __shfl_xor(rs, 32);
      lrun[qg] = lrun[qg] * corrv[qg] + rs;
      mrun[qg] = mnew;
    }

    // rescale o: corr for row q = qw+qg*16+(lg*4+r) lives in lane (lg*4+r)
#pragma unroll
    for (int qg = 0; qg < 2; ++qg)
#pragma unroll
      for (int r = 0; r < 4; ++r) {
        const float c = __shfl(corrv[qg], lg*4 + r);
#pragma unroll
        for (int ni = 0; ni < 4; ++ni) o[qg][ni][r] *= c;
      }

    // PV: O += P(32x64) V(64x64); A-frag via wave-private LDS round-trip
    bf16x8 pf[2][2];
#pragma unroll
    for (int qg = 0; qg < 2; ++qg)
#pragma unroll
      for (int ks = 0; ks < 2; ++ks)
        pf[qg][ks] = *(const bf16x8*)(sp + (qg*16 + lr)*72 + ks*32 + lk);
    __builtin_amdgcn_s_setprio(1);
#pragma unroll
    for (int qg = 0; qg < 2; ++qg)
#pragma unroll
      for (int ni = 0; ni < 4; ++ni) {
        o[qg][ni] = MFMA16(pf[qg][0], vb[ni][0], o[qg][ni]);
        o[qg][ni] = MFMA16(pf[qg][1], vb[ni][1], o[qg][ni]);
      }
    __builtin_amdgcn_s_setprio(0);
  }

  // normalize + write (1/l for row q = qw+qg*16+lg*4+r lives in lane lg*4+r)
#pragma unroll
  for (int qg = 0; qg < 2; ++qg)
#pragma unroll
    for (int r = 0; r < 4; ++r) {
      const float linv = 1.0f / __shfl(lrun[qg], lg*4 + r);
      const int qr = qw + qg*16 + lg*4 + r;
      __hip_bfloat16* op = out + (rowbase + qr) * (NHH * DHH) + hh * DHH;
#pragma unroll
      for (int ni = 0; ni < 4; ++ni)
        op[ni*16 + lr] = __float2bfloat16(o[qg][ni][r] * linv);
    }
}

// ---------------- launch ----------------
extern "C" void kernel_launch(void* const* d_in, const int* in_sizes, int n_in,
                              void* d_out, int out_size, void* d_ws, size_t ws_size,
                              hipStream_t stream) {
  (void)in_sizes; (void)n_in; (void)out_size; (void)ws_size;
  const float* x    = (const float*)d_in[0];
  const float* Wa   = (const float*)d_in[1];
  const float* Wout = (const float*)d_in[2];
  const float* bout = (const float*)d_in[3];
  const float* W1   = (const float*)d_in[4];
  const float* b1   = (const float*)d_in[5];
  const float* W2   = (const float*)d_in[6];
  const float* b2   = (const float*)d_in[7];
  const float* g1   = (const float*)d_in[8];
  const float* be1  = (const float*)d_in[9];
  const float* g2   = (const float*)d_in[10];
  const float* be2  = (const float*)d_in[11];

  char* ws = (char*)d_ws;
  __hip_bfloat16* WaT   = (__hip_bfloat16*)(ws + 0);         // [0,6M)
  __hip_bfloat16* WoutT = (__hip_bfloat16*)(ws + 6291456);   // [6,8M)
  __hip_bfloat16* W1T   = (__hip_bfloat16*)(ws + 8388608);   // [8,16M)
  __hip_bfloat16* W2T   = (__hip_bfloat16*)(ws + 16777216);  // [16,24M)
  __hip_bfloat16* o1    = (__hip_bfloat16*)(ws + 25165824);  // [24,32M)
  __hip_bfloat16* qkv   = (__hip_bfloat16*)(ws + 33554432);  // [32,56M)
  __hip_bfloat16* VT    = (__hip_bfloat16*)(ws + 58720256);  // [56,64M)
  __hip_bfloat16* attnb = (__hip_bfloat16*)(ws + 67108864);  // [64,72M)
  float*          ybuf  = (float*)(ws + 33554432);           // alias qkv
  __hip_bfloat16* ln2b  = (__hip_bfloat16*)(ws + 25165824);  // alias o1
  __hip_bfloat16* hbuf  = (__hip_bfloat16*)(ws + 50331648);  // [48,80M)
  float*          P0    = (float*)(ws + 0);                  // alias weights
  float*          P1    = (float*)(ws + 33554432);           // alias ybuf

  convT_kernel<<<dim3(NQKV/32, EE/32), 256, 0, stream>>>(Wa, WaT, EE, NQKV);
  convT_kernel<<<dim3(EE/32, EE/32), 256, 0, stream>>>(Wout, WoutT, EE, EE);
  convT_kernel<<<dim3(HIDD/32, EE/32), 256, 0, stream>>>(W1, W1T, EE, HIDD);
  convT_kernel<<<dim3(EE/32, HIDD/32), 256, 0, stream>>>(W2, W2T, HIDD, EE);
  ln_kernel<<<MTOK, 256, 0, stream>>>(x, g1, be1, o1);
  gemm_qkv<<<dim3(NQKV/128, MTOK/128), 256, 0, stream>>>(o1, WaT, qkv);
  vtrans_kernel<<<dim3(LL/32, DHH/32, BB*NHH), 256, 0, stream>>>(qkv, VT);
  attn_kernel<<<dim3(LL/128, NHH, BB), 256, 0, stream>>>(qkv, VT, attnb);
  gemm_wout<<<dim3(EE/128, MTOK/128), 256, 0, stream>>>(attnb, WoutT, ybuf, bout, x);
  ln_kernel<<<MTOK, 256, 0, stream>>>(ybuf, g2, be2, ln2b);
  gemm_ffn1<<<dim3(HIDD/128, MTOK/128), 256, 0, stream>>>(ln2b, W1T, hbuf, b1);
  gemm_ffn2p<<<dim3(EE/64, MTOK/128, 2), 256, 0, stream>>>(hbuf, W2T, P0, P1);
  ffn2_reduce<<<2048, 256, 0, stream>>>((const float4*)P0, (const float4*)P1,
                                        (const float4*)x, b2, (float4*)d_out);
}